// Round 1
// baseline (337.521 us; speedup 1.0000x reference)
//
#include <hip/hip_runtime.h>
#include <math.h>

// Problem constants (from reference): B=128, N=131072, D=1
#define PF_B 128
#define PF_N 131072
#define TPB 256                 // threads per block
#define EPT 8                   // elements per thread (2 x float4)
#define EPB (TPB * EPT)         // 2048 elements per block
#define BLOCKS_PER_BATCH (PF_N / EPB)   // 64

// d_out layout: [new_particles: B*N floats][w: B*N floats]

__global__ __launch_bounds__(TPB) void pf_compute(
    const float* __restrict__ particles,
    const float* __restrict__ weights,
    const float* __restrict__ obs,        // [B]
    const float* __restrict__ noise,
    const int*   __restrict__ tstep,      // [1]
    float* __restrict__ np_out,           // [B*N]
    float* __restrict__ w_out,            // [B*N] (unnormalized after this pass)
    float* __restrict__ sums)             // [B] (pre-zeroed)
{
    const int b     = blockIdx.x / BLOCKS_PER_BATCH;
    const int chunk = blockIdx.x % BLOCKS_PER_BATCH;
    const long base = (long)b * PF_N + (long)chunk * EPB;

    const float ob  = obs[b];
    const float c   = 8.0f * cosf(1.2f * (float)(*tstep));
    const float sq10 = 3.16227770f;              // np.float32(sqrt(10))
    const float nhl2pi = -0.9189385f;            // -0.5*log(2*pi) in fp32

    float lsum = 0.0f;

    #pragma unroll
    for (int k = 0; k < EPT / 4; ++k) {
        const long idx = base + (long)k * (TPB * 4) + (long)threadIdx.x * 4;
        const float4 x4  = *(const float4*)(particles + idx);
        const float4 n4  = *(const float4*)(noise + idx);
        const float4 wt4 = *(const float4*)(weights + idx);

        float xs[4] = {x4.x, x4.y, x4.z, x4.w};
        float ns[4] = {n4.x, n4.y, n4.z, n4.w};
        float ws[4] = {wt4.x, wt4.y, wt4.z, wt4.w};
        float xn[4], wn[4];

        #pragma unroll
        for (int j = 0; j < 4; ++j) {
            const float x = xs[j];
            // mean = x/2 + 25*x/(x^2+1) + 8*cos(1.2*t)
            const float mean = x * 0.5f + 25.0f * (x / (x * x + 1.0f)) + c;
            const float xnew = mean + ns[j] * sq10;
            xn[j] = xnew;
            const float om = (xnew * xnew) / 20.0f;
            const float d  = ob - om;
            const float lp = -0.5f * d * d + nhl2pi;
            const float wv = ws[j] * expf(lp);
            wn[j] = wv;
            lsum += wv;
        }

        float4 o4; o4.x = xn[0]; o4.y = xn[1]; o4.z = xn[2]; o4.w = xn[3];
        float4 w4; w4.x = wn[0]; w4.y = wn[1]; w4.z = wn[2]; w4.w = wn[3];
        *(float4*)(np_out + idx) = o4;
        *(float4*)(w_out + idx)  = w4;
    }

    // wave (64-lane) reduction, then cross-wave via LDS, one atomic per block
    #pragma unroll
    for (int off = 32; off > 0; off >>= 1)
        lsum += __shfl_down(lsum, off, 64);

    __shared__ float red[TPB / 64];
    if ((threadIdx.x & 63) == 0) red[threadIdx.x >> 6] = lsum;
    __syncthreads();
    if (threadIdx.x == 0) {
        float s = 0.0f;
        #pragma unroll
        for (int i = 0; i < TPB / 64; ++i) s += red[i];
        atomicAdd(&sums[b], s);
    }
}

__global__ __launch_bounds__(TPB) void pf_normalize(
    float* __restrict__ w_out,
    const float* __restrict__ sums)
{
    const int b     = blockIdx.x / BLOCKS_PER_BATCH;
    const int chunk = blockIdx.x % BLOCKS_PER_BATCH;
    const long base = (long)b * PF_N + (long)chunk * EPB;
    const float inv = 1.0f / sums[b];

    #pragma unroll
    for (int k = 0; k < EPT / 4; ++k) {
        const long idx = base + (long)k * (TPB * 4) + (long)threadIdx.x * 4;
        float4 v = *(const float4*)(w_out + idx);
        v.x *= inv; v.y *= inv; v.z *= inv; v.w *= inv;
        *(float4*)(w_out + idx) = v;
    }
}

extern "C" void kernel_launch(void* const* d_in, const int* in_sizes, int n_in,
                              void* d_out, int out_size, void* d_ws, size_t ws_size,
                              hipStream_t stream) {
    const float* particles = (const float*)d_in[0];
    const float* weights   = (const float*)d_in[1];
    const float* obs       = (const float*)d_in[2];
    const float* noise     = (const float*)d_in[3];
    // d_in[4] = uniforms: dead code in the reference (resample output unused)
    const int*   tstep     = (const int*)d_in[5];

    float* np_out = (float*)d_out;                     // new_particles [B*N]
    float* w_out  = (float*)d_out + (long)PF_B * PF_N; // weights      [B*N]
    float* sums   = (float*)d_ws;                      // [B]

    hipMemsetAsync(d_ws, 0, PF_B * sizeof(float), stream);

    const int grid = PF_B * BLOCKS_PER_BATCH;  // 8192 blocks
    pf_compute<<<grid, TPB, 0, stream>>>(particles, weights, obs, noise, tstep,
                                         np_out, w_out, sums);
    pf_normalize<<<grid, TPB, 0, stream>>>(w_out, sums);
}